// Round 2
// baseline (681.071 us; speedup 1.0000x reference)
//
#include <hip/hip_runtime.h>
#include <stdint.h>

// ---------------------------------------------------------------------------
// MultiHeadLinearAttention (B=4,S=8192,D=512,H=8,dk=64), fp32 in/out.
// Round 2: proj/out_gemm rebuilt m97-style — bf16 pre-convert + async
// global_load_lds(16B) staging with XOR bank-swizzle; B-frags direct global.
// Pipeline:
//   1. convert_weights: 7 [512,512] fp32 -> bf16
//   2. convert_x: q,k,v fp32 -> bf16 (xbf)
//   3. proj_kernel: phi(silu(XW1^T+b1)*(XW2^T+b2)) -> bf16 [32768,512]
//   4. kv_kernel: split-K partial KV^T + ksum
//   5. kv_reduce -> kvT bf16 [bh][e][d], ksum_bf
//   6. attn_kernel: numerator + qk_sum (broadcast-B MFMA), fused divide
//   7. out_gemm: x_attn @ out_w^T + out_b -> fp32
// MFMA 16x16x32_bf16 layouts (verified m89/m91):
//   A: m=lane&15, k=quad*8+j ; B: n=lane&15, k=quad*8+j
//   D: col=lane&15, row=quad*4+r
// LDS swizzle: logical (row, octet e8) stored at row*64 + ((e8^(row&7))*8).
// global_load_lds writes base+lane*16, so lane l of issue ig loads global
// octet kq=(l&7)^(l>>3) of row ig*8+(l>>3) -> lands at the swizzled slot.
// ---------------------------------------------------------------------------

#define DMODEL 512
#define NHEAD 8
#define BATCH 4
#define SEQ 8192
#define BSROWS (BATCH * SEQ) // 32768
#define NSPLIT 16
#define CHUNK (SEQ / NSPLIT) // 512

typedef __attribute__((ext_vector_type(8))) short short8;
typedef __attribute__((ext_vector_type(4))) short short4v;
typedef __attribute__((ext_vector_type(4))) float f32x4;
typedef __attribute__((ext_vector_type(4))) unsigned short ushort4v;

__device__ __forceinline__ unsigned short f2bf(float f) {
  union { float f; uint32_t u; } v; v.f = f;
  uint32_t u = v.u;
  u += 0x7fffu + ((u >> 16) & 1u); // RNE
  return (unsigned short)(u >> 16);
}
__device__ __forceinline__ float bf2f(unsigned short h) {
  union { float f; uint32_t u; } v; v.u = ((uint32_t)h) << 16; return v.f;
}
__device__ __forceinline__ f32x4 zero4() {
  f32x4 z; z[0] = 0.f; z[1] = 0.f; z[2] = 0.f; z[3] = 0.f; return z;
}
__device__ __forceinline__ void gload_lds16(const unsigned short* g, unsigned short* l) {
  __builtin_amdgcn_global_load_lds((const __attribute__((address_space(1))) void*)g,
                                   (__attribute__((address_space(3))) void*)l, 16, 0, 0);
}

// ---------------------------------------------------------------------------
struct WPtrs { const float* w[7]; };

__global__ void convert_weights_kernel(WPtrs wp, unsigned short* __restrict__ wbf) {
  int gid = blockIdx.x * 256 + threadIdx.x;  // 458752 total
  int which = gid >> 16;                     // 65536 float4 per matrix
  int rem = gid & 65535;
  float4 v = ((const float4*)wp.w[which])[rem];
  ushort4v o;
  o[0] = f2bf(v.x); o[1] = f2bf(v.y); o[2] = f2bf(v.z); o[3] = f2bf(v.w);
  *(ushort4v*)(wbf + (size_t)which * 262144 + (size_t)rem * 4) = o;
}

__global__ void convert_x_kernel(const float* __restrict__ q, const float* __restrict__ k,
                                 const float* __restrict__ v, unsigned short* __restrict__ xbf) {
  size_t t = (size_t)blockIdx.x * 256 + threadIdx.x; // 6291456 threads, 8 elems each
  int which = (int)(t >> 21);
  size_t rem = t & 2097151;
  const float* src = which == 0 ? q : (which == 1 ? k : v);
  const float4* s4 = (const float4*)src + rem * 2;
  float4 a = s4[0], b = s4[1];
  short8 o;
  o[0] = (short)f2bf(a.x); o[1] = (short)f2bf(a.y);
  o[2] = (short)f2bf(a.z); o[3] = (short)f2bf(a.w);
  o[4] = (short)f2bf(b.x); o[5] = (short)f2bf(b.y);
  o[6] = (short)f2bf(b.z); o[7] = (short)f2bf(b.w);
  *(short8*)(xbf + ((size_t)which << 24) + rem * 8) = o;
}

// ---------------------------------------------------------------------------
// Gated projection: out = phi?(silu(X@W1^T+b1) * (X@W2^T+b2)).
// 128x128 tile, 4 waves x (64x64) with dual accumulators (W1,W2).
// A: bf16 via global_load_lds + XOR swizzle. B: direct global (L2-hot, 3 MB).
struct ProjArgs {
  const float* b1[3];
  const float* b2[3];
  unsigned short* out[3];
};

__global__ __launch_bounds__(256, 2) void proj_kernel(ProjArgs pa,
                                                      const unsigned short* __restrict__ wbf,
                                                      const unsigned short* __restrict__ xbf) {
  const int which = blockIdx.y;
  const unsigned short* __restrict__ x = xbf + ((size_t)which << 24);
  const unsigned short* __restrict__ w1 = wbf + (size_t)which * 524288;
  const unsigned short* __restrict__ w2 = w1 + 262144;
  const float* __restrict__ b1p = pa.b1[which];
  const float* __restrict__ b2p = pa.b2[which];
  unsigned short* __restrict__ outp = pa.out[which];
  const bool PHI = (which < 2);

  const int mt = blockIdx.x >> 2, nt = blockIdx.x & 3;
  const int m0 = mt * 128, n0 = nt * 128;
  const int tid = threadIdx.x;
  const int wave = tid >> 6, lane = tid & 63;
  const int lrow = lane & 15, quad = lane >> 4;
  const int m_off = (wave & 1) * 64, n_off = (wave >> 1) * 64;

  __shared__ unsigned short sA[128 * 64]; // 16 KB, swizzled, no padding

  const int srow_l = lane >> 3;            // 0..7 within 8-row issue
  const int kq_l = (lane & 7) ^ srow_l;    // swizzled source octet
  const int swz = lrow & 7;

  f32x4 acc1[4][4], acc2[4][4];
#pragma unroll
  for (int i = 0; i < 4; i++)
#pragma unroll
    for (int j = 0; j < 4; j++) { acc1[i][j] = zero4(); acc2[i][j] = zero4(); }

  for (int k0 = 0; k0 < 512; k0 += 64) {
    __syncthreads();
#pragma unroll
    for (int i = 0; i < 4; i++) {
      int ig = wave * 4 + i;               // 16 issues cover 128x64
      const unsigned short* src = x + (size_t)(m0 + ig * 8 + srow_l) * 512 + k0 + kq_l * 8;
      gload_lds16(src, sA + ig * 512);
    }
    __syncthreads();
#pragma unroll
    for (int kk = 0; kk < 64; kk += 32) {
      short8 af[4];
#pragma unroll
      for (int mi = 0; mi < 4; mi++) {
        int r = m_off + mi * 16 + lrow;
        int e8 = (kk >> 3) + quad;
        af[mi] = *(const short8*)(sA + r * 64 + (((e8 ^ swz) << 3)));
      }
#pragma unroll
      for (int ni = 0; ni < 4; ni++) {
        const size_t boff = (size_t)(n0 + n_off + ni * 16 + lrow) * 512 + k0 + kk + quad * 8;
        short8 bw1 = *(const short8*)(w1 + boff);
        short8 bw2 = *(const short8*)(w2 + boff);
#pragma unroll
        for (int mi = 0; mi < 4; mi++) {
          acc1[mi][ni] = __builtin_amdgcn_mfma_f32_16x16x32_bf16(af[mi], bw1, acc1[mi][ni], 0, 0, 0);
          acc2[mi][ni] = __builtin_amdgcn_mfma_f32_16x16x32_bf16(af[mi], bw2, acc2[mi][ni], 0, 0, 0);
        }
      }
    }
  }
#pragma unroll
  for (int ni = 0; ni < 4; ni++) {
    int n = n0 + n_off + ni * 16 + lrow;
    float bb1 = b1p[n], bb2 = b2p[n];
#pragma unroll
    for (int mi = 0; mi < 4; mi++) {
#pragma unroll
      for (int r = 0; r < 4; r++) {
        int m = m0 + m_off + mi * 16 + quad * 4 + r;
        float v1 = acc1[mi][ni][r] + bb1;
        float v2 = acc2[mi][ni][r] + bb2;
        float y = v1 * (1.f / (1.f + __expf(-v1))) * v2; // silu(v1)*v2
        if (PHI) y = (y > 0.f) ? (y + 1.f) : __expf(y);  // elu(y)+1
        outp[(size_t)m * 512 + n] = f2bf(y);
      }
    }
  }
}

// ---------------------------------------------------------------------------
// KV^T partials: per (bh, chunk) block computes D[e][d] = sum_s v[s,e]*phik[s,d]
// over 512 rows (4 stages of 128; each wave owns a 32-row K-slice), plus
// ksum[d] = sum_s phik[s,d] accumulated during staging.
#define KVPITCH 68

__global__ __launch_bounds__(256, 2) void kv_kernel(const unsigned short* __restrict__ phiK,
                                                    const unsigned short* __restrict__ vP,
                                                    float* __restrict__ kvt_part,
                                                    float* __restrict__ ksum_part) {
  const int chunk = blockIdx.x & (NSPLIT - 1);
  const int bh = blockIdx.x >> 4;
  const int b = bh >> 3, h = bh & 7;
  const size_t base = ((size_t)b * SEQ + (size_t)chunk * CHUNK) * 512 + h * 64;

  const int tid = threadIdx.x;
  const int wave = tid >> 6, lane = tid & 63;
  const int lrow = lane & 15, quad = lane >> 4;
  const int dchunk = tid & 7;   // staging: 8-wide d sub-chunk
  const int srow = tid >> 3;    // staging: 0..31

  __shared__ unsigned short sV[128 * KVPITCH];
  __shared__ unsigned short sK[128 * KVPITCH];
  __shared__ float ls_acc[4096];
  __shared__ float ls_ksum[64];

  if (tid < 64) ls_ksum[tid] = 0.f;

  float ksum_th[8];
#pragma unroll
  for (int j = 0; j < 8; j++) ksum_th[j] = 0.f;

  f32x4 acc[4][4];
#pragma unroll
  for (int i = 0; i < 4; i++)
#pragma unroll
    for (int j = 0; j < 4; j++) acc[i][j] = zero4();

  for (int st = 0; st < 4; st++) {
    __syncthreads();
#pragma unroll
    for (int i = 0; i < 4; i++) {
      int s = srow + i * 32;
      size_t g = base + (size_t)(st * 128 + s) * 512 + dchunk * 8;
      short8 v8 = *(const short8*)(vP + g);
      short8 k8 = *(const short8*)(phiK + g);
      short4v vlo = __builtin_shufflevector(v8, v8, 0, 1, 2, 3);
      short4v vhi = __builtin_shufflevector(v8, v8, 4, 5, 6, 7);
      short4v klo = __builtin_shufflevector(k8, k8, 0, 1, 2, 3);
      short4v khi = __builtin_shufflevector(k8, k8, 4, 5, 6, 7);
      *(short4v*)(sV + s * KVPITCH + dchunk * 8) = vlo;
      *(short4v*)(sV + s * KVPITCH + dchunk * 8 + 4) = vhi;
      *(short4v*)(sK + s * KVPITCH + dchunk * 8) = klo;
      *(short4v*)(sK + s * KVPITCH + dchunk * 8 + 4) = khi;
#pragma unroll
      for (int j = 0; j < 8; j++) ksum_th[j] += bf2f((unsigned short)k8[j]);
    }
    __syncthreads();
    const int sbase = wave * 32;
    short8 af[4], bfr[4];
#pragma unroll
    for (int mi = 0; mi < 4; mi++) {
      short8 a;
#pragma unroll
      for (int j = 0; j < 8; j++)
        a[j] = (short)sV[(sbase + quad * 8 + j) * KVPITCH + mi * 16 + lrow];
      af[mi] = a;
    }
#pragma unroll
    for (int ni = 0; ni < 4; ni++) {
      short8 bb;
#pragma unroll
      for (int j = 0; j < 8; j++)
        bb[j] = (short)sK[(sbase + quad * 8 + j) * KVPITCH + ni * 16 + lrow];
      bfr[ni] = bb;
    }
#pragma unroll
    for (int mi = 0; mi < 4; mi++)
#pragma unroll
      for (int ni = 0; ni < 4; ni++)
        acc[mi][ni] = __builtin_amdgcn_mfma_f32_16x16x32_bf16(af[mi], bfr[ni], acc[mi][ni], 0, 0, 0);
  }

#pragma unroll
  for (int j = 0; j < 8; j++) atomicAdd(&ls_ksum[dchunk * 8 + j], ksum_th[j]);

  __syncthreads();
#pragma unroll
  for (int i = 0; i < 16; i++) ls_acc[tid + 256 * i] = 0.f;
  __syncthreads();
#pragma unroll
  for (int mi = 0; mi < 4; mi++)
#pragma unroll
    for (int ni = 0; ni < 4; ni++)
#pragma unroll
      for (int r = 0; r < 4; r++)
        atomicAdd(&ls_acc[(mi * 16 + quad * 4 + r) * 64 + ni * 16 + lrow], acc[mi][ni][r]);
  __syncthreads();

  float* op = kvt_part + ((size_t)chunk * 32 + bh) * 4096;
#pragma unroll
  for (int i = 0; i < 16; i++) op[tid + 256 * i] = ls_acc[tid + 256 * i];
  if (tid < 64) ksum_part[((size_t)chunk * 32 + bh) * 64 + tid] = ls_ksum[tid];
}

// ---------------------------------------------------------------------------
__global__ void kv_reduce_kernel(const float* __restrict__ kvt_part,
                                 const float* __restrict__ ksum_part,
                                 unsigned short* __restrict__ kvT,
                                 unsigned short* __restrict__ ksum_bf) {
  int bh = blockIdx.x, tid = threadIdx.x;
#pragma unroll
  for (int i = 0; i < 16; i++) {
    int idx = tid + 256 * i;
    float s = 0.f;
#pragma unroll
    for (int c = 0; c < NSPLIT; c++) s += kvt_part[((size_t)c * 32 + bh) * 4096 + idx];
    kvT[(size_t)bh * 4096 + idx] = f2bf(s);
  }
  if (tid < 64) {
    float s = 0.f;
#pragma unroll
    for (int c = 0; c < NSPLIT; c++) s += ksum_part[((size_t)c * 32 + bh) * 64 + tid];
    ksum_bf[bh * 64 + tid] = f2bf(s);
  }
}

// ---------------------------------------------------------------------------
// numerator = phiQ @ KV, qk_sum = phiQ @ ksum (broadcast-column B => extra
// MFMA whose D rows line up lane-for-lane with the numerator rows).
__global__ __launch_bounds__(256) void attn_kernel(const unsigned short* __restrict__ phiQ,
                                                   const unsigned short* __restrict__ kvT,
                                                   const unsigned short* __restrict__ ksum_bf,
                                                   unsigned short* __restrict__ xattn) {
  const int bh = blockIdx.x & 31;
  const int st = blockIdx.x >> 5;
  const int b = bh >> 3, h = bh & 7;
  const int tid = threadIdx.x;
  const int wave = tid >> 6, lane = tid & 63;
  const int lrow = lane & 15, quad = lane >> 4;
  const size_t rowbase = (size_t)b * SEQ + st * 128 + wave * 32;

  f32x4 acc[2][4], aqs[2];
#pragma unroll
  for (int i = 0; i < 2; i++) {
    aqs[i] = zero4();
#pragma unroll
    for (int j = 0; j < 4; j++) acc[i][j] = zero4();
  }

#pragma unroll
  for (int kk = 0; kk < 64; kk += 32) {
    short8 ks = *(const short8*)(ksum_bf + bh * 64 + kk + quad * 8);
    short8 af[2];
#pragma unroll
    for (int mi = 0; mi < 2; mi++)
      af[mi] = *(const short8*)(phiQ + (rowbase + mi * 16 + lrow) * 512 + h * 64 + kk + quad * 8);
#pragma unroll
    for (int mi = 0; mi < 2; mi++)
      aqs[mi] = __builtin_amdgcn_mfma_f32_16x16x32_bf16(af[mi], ks, aqs[mi], 0, 0, 0);
#pragma unroll
    for (int ni = 0; ni < 4; ni++) {
      short8 bfr = *(const short8*)(kvT + (size_t)bh * 4096 + (ni * 16 + lrow) * 64 + kk + quad * 8);
#pragma unroll
      for (int mi = 0; mi < 2; mi++)
        acc[mi][ni] = __builtin_amdgcn_mfma_f32_16x16x32_bf16(af[mi], bfr, acc[mi][ni], 0, 0, 0);
    }
  }
#pragma unroll
  for (int mi = 0; mi < 2; mi++) {
#pragma unroll
    for (int r = 0; r < 4; r++) {
      float inv = 1.f / (aqs[mi][r] + 1e-6f);
      size_t m = rowbase + mi * 16 + quad * 4 + r;
#pragma unroll
      for (int ni = 0; ni < 4; ni++)
        xattn[m * 512 + h * 64 + ni * 16 + lrow] = f2bf(acc[mi][ni][r] * inv);
    }
  }
}

// ---------------------------------------------------------------------------
__global__ __launch_bounds__(256, 2) void out_gemm_kernel(const unsigned short* __restrict__ xattn,
                                                          const unsigned short* __restrict__ wo,
                                                          const float* __restrict__ ob,
                                                          float* __restrict__ out) {
  const int mt = blockIdx.x >> 2, nt = blockIdx.x & 3;
  const int m0 = mt * 128, n0 = nt * 128;
  const int tid = threadIdx.x;
  const int wave = tid >> 6, lane = tid & 63;
  const int lrow = lane & 15, quad = lane >> 4;
  const int m_off = (wave & 1) * 64, n_off = (wave >> 1) * 64;

  __shared__ unsigned short sA[128 * 64];

  const int srow_l = lane >> 3;
  const int kq_l = (lane & 7) ^ srow_l;
  const int swz = lrow & 7;

  f32x4 acc[4][4];
#pragma unroll
  for (int i = 0; i < 4; i++)
#pragma unroll
    for (int j = 0; j < 4; j++) acc[i][j] = zero4();

  for (int k0 = 0; k0 < 512; k0 += 64) {
    __syncthreads();
#pragma unroll
    for (int i = 0; i < 4; i++) {
      int ig = wave * 4 + i;
      const unsigned short* src = xattn + (size_t)(m0 + ig * 8 + srow_l) * 512 + k0 + kq_l * 8;
      gload_lds16(src, sA + ig * 512);
    }
    __syncthreads();
#pragma unroll
    for (int kk = 0; kk < 64; kk += 32) {
      short8 af[4];
#pragma unroll
      for (int mi = 0; mi < 4; mi++) {
        int r = m_off + mi * 16 + lrow;
        int e8 = (kk >> 3) + quad;
        af[mi] = *(const short8*)(sA + r * 64 + (((e8 ^ swz) << 3)));
      }
#pragma unroll
      for (int ni = 0; ni < 4; ni++) {
        short8 bfr = *(const short8*)(wo + (size_t)(n0 + n_off + ni * 16 + lrow) * 512 + k0 + kk + quad * 8);
#pragma unroll
        for (int mi = 0; mi < 4; mi++)
          acc[mi][ni] = __builtin_amdgcn_mfma_f32_16x16x32_bf16(af[mi], bfr, acc[mi][ni], 0, 0, 0);
      }
    }
  }
#pragma unroll
  for (int ni = 0; ni < 4; ni++) {
    int n = n0 + n_off + ni * 16 + lrow;
    float bb = ob[n];
#pragma unroll
    for (int mi = 0; mi < 4; mi++)
#pragma unroll
      for (int r = 0; r < 4; r++) {
        int m = m0 + m_off + mi * 16 + quad * 4 + r;
        out[(size_t)m * 512 + n] = acc[mi][ni][r] + bb;
      }
  }
}

// ---------------------------------------------------------------------------
extern "C" void kernel_launch(void* const* d_in, const int* in_sizes, int n_in,
                              void* d_out, int out_size, void* d_ws, size_t ws_size,
                              hipStream_t stream) {
  char* ws = (char*)d_ws;
  size_t off = 0;
  auto alloc = [&](size_t bytes) -> void* {
    void* p = ws + off;
    off += (bytes + 255) & ~(size_t)255;
    return p;
  };
  unsigned short* wbf = (unsigned short*)alloc((size_t)7 * 262144 * 2);  // 3.67 MB
  unsigned short* phiQ = (unsigned short*)alloc((size_t)BSROWS * 512 * 2);
  unsigned short* phiK = (unsigned short*)alloc((size_t)BSROWS * 512 * 2); // reused as x_attn
  unsigned short* vP = (unsigned short*)alloc((size_t)BSROWS * 512 * 2);
  unsigned short* xbf = (unsigned short*)alloc((size_t)3 * BSROWS * 512 * 2); // 100.7 MB
  if (off > ws_size) return; // insufficient workspace; fail visibly

  // kv partials alias xbf (xbf dead after proj_kernel completes)
  char* xr = (char*)xbf;
  float* kvt_part = (float*)xr;                          // 8,388,608 B
  float* ksum_part = (float*)(xr + 8388608);             //   131,072 B
  unsigned short* kvT = (unsigned short*)(xr + 8519680); //   262,144 B
  unsigned short* ksum_bf = (unsigned short*)(xr + 8781824);

  WPtrs wp;
  for (int i = 0; i < 7; i++) wp.w[i] = (const float*)d_in[3 + i];
  convert_weights_kernel<<<1792, 256, 0, stream>>>(wp, wbf);
  convert_x_kernel<<<24576, 256, 0, stream>>>((const float*)d_in[0], (const float*)d_in[1],
                                              (const float*)d_in[2], xbf);

  ProjArgs pa;
  pa.b1[0] = (const float*)d_in[10]; pa.b2[0] = (const float*)d_in[11];
  pa.b1[1] = (const float*)d_in[12]; pa.b2[1] = (const float*)d_in[13];
  pa.b1[2] = (const float*)d_in[14]; pa.b2[2] = (const float*)d_in[15];
  pa.out[0] = phiQ; pa.out[1] = phiK; pa.out[2] = vP;
  proj_kernel<<<dim3(1024, 3), 256, 0, stream>>>(pa, wbf, xbf);

  kv_kernel<<<512, 256, 0, stream>>>(phiK, vP, kvt_part, ksum_part);
  kv_reduce_kernel<<<32, 256, 0, stream>>>(kvt_part, ksum_part, kvT, ksum_bf);
  attn_kernel<<<2048, 256, 0, stream>>>(phiQ, kvT, ksum_bf, phiK /* x_attn alias */);
  out_gemm_kernel<<<1024, 256, 0, stream>>>(phiK, wbf + (size_t)6 * 262144,
                                            (const float*)d_in[16], (float*)d_out);
}

// Round 3
// 483.466 us; speedup vs baseline: 1.4087x; 1.4087x over previous
//
#include <hip/hip_runtime.h>
#include <stdint.h>

// ---------------------------------------------------------------------------
// MultiHeadLinearAttention (B=4,S=8192,D=512,H=8,dk=64), fp32 in/out.
// Round 3: proj/out_gemm use full m97 structure (A AND B staged via
// global_load_lds + XOR swizzle, ds_read_b128 fragments). phiK/vP are written
// TRANSPOSED ([bh][d][s]) by proj so kv_kernel is a clean contiguous-k GEMM
// (no scalar LDS reads); ksum computed with a ones-A MFMA.
// Pipeline:
//   1. convert_weights: 7 [512,512] fp32 -> bf16
//   2. convert_x: q,k,v fp32 -> bf16 (xbf)
//   3. proj_kernel: phi(silu(XW1^T+b1)*(XW2^T+b2))
//        which=0 -> phiQ [m][n] ; which=1 -> kT [bh][d][s] ; which=2 -> vT
//   4. kv_kernel: per (bh,chunk) GEMM D[e][d]=sum_s vT[e][s]*kT[d][s] + ksum
//   5. kv_reduce -> kvT bf16 [bh][e][d], ksum_bf
//   6. attn_kernel: numerator + qk_sum (broadcast-B MFMA), fused divide
//   7. out_gemm: x_attn @ out_w^T + out_b -> fp32
// MFMA 16x16x32_bf16 layouts (verified m89/m91):
//   A: m=lane&15, k=quad*8+j ; B: n=lane&15, k=quad*8+j
//   D: col=lane&15, row=quad*4+r
// LDS swizzle: logical (row, octet e8) stored at row*64 + ((e8^(row&7))*8);
// global_load_lds lane l of issue ig fetches octet (l&7)^(l>>3) of row
// ig*8+(l>>3) so it lands at the swizzled slot. (Round-2 verified: 0 bank
// conflicts, correct results.)
// ---------------------------------------------------------------------------

#define DMODEL 512
#define NHEAD 8
#define BATCH 4
#define SEQ 8192
#define BSROWS (BATCH * SEQ) // 32768
#define NSPLIT 16
#define CHUNK (SEQ / NSPLIT) // 512

typedef __attribute__((ext_vector_type(8))) short short8;
typedef __attribute__((ext_vector_type(4))) short short4v;
typedef __attribute__((ext_vector_type(4))) float f32x4;
typedef __attribute__((ext_vector_type(4))) unsigned short ushort4v;

__device__ __forceinline__ unsigned short f2bf(float f) {
  union { float f; uint32_t u; } v; v.f = f;
  uint32_t u = v.u;
  u += 0x7fffu + ((u >> 16) & 1u); // RNE
  return (unsigned short)(u >> 16);
}
__device__ __forceinline__ float bf2f(unsigned short h) {
  union { float f; uint32_t u; } v; v.u = ((uint32_t)h) << 16; return v.f;
}
__device__ __forceinline__ f32x4 zero4() {
  f32x4 z; z[0] = 0.f; z[1] = 0.f; z[2] = 0.f; z[3] = 0.f; return z;
}
__device__ __forceinline__ void gload_lds16(const unsigned short* g, unsigned short* l) {
  __builtin_amdgcn_global_load_lds((const __attribute__((address_space(1))) void*)g,
                                   (__attribute__((address_space(3))) void*)l, 16, 0, 0);
}

// ---------------------------------------------------------------------------
struct WPtrs { const float* w[7]; };

__global__ void convert_weights_kernel(WPtrs wp, unsigned short* __restrict__ wbf) {
  int gid = blockIdx.x * 256 + threadIdx.x;  // 458752 total
  int which = gid >> 16;                     // 65536 float4 per matrix
  int rem = gid & 65535;
  float4 v = ((const float4*)wp.w[which])[rem];
  ushort4v o;
  o[0] = f2bf(v.x); o[1] = f2bf(v.y); o[2] = f2bf(v.z); o[3] = f2bf(v.w);
  *(ushort4v*)(wbf + (size_t)which * 262144 + (size_t)rem * 4) = o;
}

__global__ void convert_x_kernel(const float* __restrict__ q, const float* __restrict__ k,
                                 const float* __restrict__ v, unsigned short* __restrict__ xbf) {
  size_t t = (size_t)blockIdx.x * 256 + threadIdx.x; // 6291456 threads, 8 elems each
  int which = (int)(t >> 21);
  size_t rem = t & 2097151;
  const float* src = which == 0 ? q : (which == 1 ? k : v);
  const float4* s4 = (const float4*)src + rem * 2;
  float4 a = s4[0], b = s4[1];
  short8 o;
  o[0] = (short)f2bf(a.x); o[1] = (short)f2bf(a.y);
  o[2] = (short)f2bf(a.z); o[3] = (short)f2bf(a.w);
  o[4] = (short)f2bf(b.x); o[5] = (short)f2bf(b.y);
  o[6] = (short)f2bf(b.z); o[7] = (short)f2bf(b.w);
  *(short8*)(xbf + ((size_t)which << 24) + rem * 8) = o;
}

// ---------------------------------------------------------------------------
// Gated projection: 128x128 tile, 4 waves x (64x64), dual accumulators.
// A, W1, W2 all staged in LDS via global_load_lds (m97 structure).
struct ProjArgs {
  const float* b1[3];
  const float* b2[3];
  unsigned short* out[3]; // which0: phiQ [m][512]; which1/2: [bh][d][8192]
};

__global__ __launch_bounds__(256, 2) void proj_kernel(ProjArgs pa,
                                                      const unsigned short* __restrict__ wbf,
                                                      const unsigned short* __restrict__ xbf) {
  const int which = blockIdx.y;
  const unsigned short* __restrict__ x = xbf + ((size_t)which << 24);
  const unsigned short* __restrict__ w1 = wbf + (size_t)which * 524288;
  const unsigned short* __restrict__ w2 = w1 + 262144;
  const float* __restrict__ b1p = pa.b1[which];
  const float* __restrict__ b2p = pa.b2[which];
  unsigned short* __restrict__ outp = pa.out[which];
  const bool PHI = (which < 2);

  const int mt = blockIdx.x >> 2, nt = blockIdx.x & 3;
  const int m0 = mt * 128, n0 = nt * 128;
  const int tid = threadIdx.x;
  const int wave = tid >> 6, lane = tid & 63;
  const int lrow = lane & 15, quad = lane >> 4;
  const int m_off = (wave & 1) * 64, n_off = (wave >> 1) * 64;

  __shared__ unsigned short sA[128 * 64];  // 16 KB each, swizzled
  __shared__ unsigned short sB1[128 * 64];
  __shared__ unsigned short sB2[128 * 64];

  const int srow_l = lane >> 3;            // 0..7 within 8-row issue
  const int kq_l = (lane & 7) ^ srow_l;    // swizzled source octet
  const int swz = lrow & 7;

  f32x4 acc1[4][4], acc2[4][4];
#pragma unroll
  for (int i = 0; i < 4; i++)
#pragma unroll
    for (int j = 0; j < 4; j++) { acc1[i][j] = zero4(); acc2[i][j] = zero4(); }

  for (int k0 = 0; k0 < 512; k0 += 64) {
    __syncthreads();
#pragma unroll
    for (int i = 0; i < 4; i++) {
      int ig = wave * 4 + i;               // 16 issues cover each 128x64 tile
      size_t roff = (size_t)(ig * 8 + srow_l) * 512 + k0 + kq_l * 8;
      gload_lds16(x + (size_t)m0 * 512 + roff, sA + ig * 512);
      gload_lds16(w1 + (size_t)n0 * 512 + roff, sB1 + ig * 512);
      gload_lds16(w2 + (size_t)n0 * 512 + roff, sB2 + ig * 512);
    }
    __syncthreads();
#pragma unroll
    for (int kk = 0; kk < 64; kk += 32) {
      const int e8 = (kk >> 3) + quad;
      short8 af[4], b1f[4], b2f[4];
#pragma unroll
      for (int mi = 0; mi < 4; mi++)
        af[mi] = *(const short8*)(sA + (m_off + mi * 16 + lrow) * 64 + (((e8 ^ swz) << 3)));
#pragma unroll
      for (int ni = 0; ni < 4; ni++) {
        int rr = n_off + ni * 16 + lrow;
        b1f[ni] = *(const short8*)(sB1 + rr * 64 + (((e8 ^ swz) << 3)));
        b2f[ni] = *(const short8*)(sB2 + rr * 64 + (((e8 ^ swz) << 3)));
      }
#pragma unroll
      for (int ni = 0; ni < 4; ni++)
#pragma unroll
        for (int mi = 0; mi < 4; mi++) {
          acc1[mi][ni] = __builtin_amdgcn_mfma_f32_16x16x32_bf16(af[mi], b1f[ni], acc1[mi][ni], 0, 0, 0);
          acc2[mi][ni] = __builtin_amdgcn_mfma_f32_16x16x32_bf16(af[mi], b2f[ni], acc2[mi][ni], 0, 0, 0);
        }
    }
  }

  if (which == 0) {
#pragma unroll
    for (int ni = 0; ni < 4; ni++) {
      int n = n0 + n_off + ni * 16 + lrow;
      float bb1 = b1p[n], bb2 = b2p[n];
#pragma unroll
      for (int mi = 0; mi < 4; mi++)
#pragma unroll
        for (int r = 0; r < 4; r++) {
          int m = m0 + m_off + mi * 16 + quad * 4 + r;
          float v1 = acc1[mi][ni][r] + bb1;
          float v2 = acc2[mi][ni][r] + bb2;
          float y = v1 * (1.f / (1.f + __expf(-v1))) * v2; // silu(v1)*v2
          y = (y > 0.f) ? (y + 1.f) : __expf(y);           // elu(y)+1
          outp[(size_t)m * 512 + n] = f2bf(y);
        }
    }
  } else {
    // transposed store: [bh][d][s], 8B (4 consecutive s) per lane per (mi,ni)
    const int bI = m0 >> 13;
    const int sb = (m0 & 8191) + m_off + quad * 4;
#pragma unroll
    for (int ni = 0; ni < 4; ni++) {
      int n = n0 + n_off + ni * 16 + lrow;
      float bb1 = b1p[n], bb2 = b2p[n];
      int h = n >> 6, d = n & 63;
      unsigned short* dst0 = outp + (((size_t)bI * 8 + h) * 64 + d) * 8192 + sb;
#pragma unroll
      for (int mi = 0; mi < 4; mi++) {
        short4v o;
#pragma unroll
        for (int r = 0; r < 4; r++) {
          float v1 = acc1[mi][ni][r] + bb1;
          float v2 = acc2[mi][ni][r] + bb2;
          float y = v1 * (1.f / (1.f + __expf(-v1))) * v2;
          if (PHI) y = (y > 0.f) ? (y + 1.f) : __expf(y);
          o[r] = (short)f2bf(y);
        }
        *(short4v*)(dst0 + mi * 16) = o;
      }
    }
  }
}

// ---------------------------------------------------------------------------
// KV^T partials from transposed inputs: D[e][d] = sum_s vT[e][s]*kT[d][s].
// Per (bh,chunk) block: 4 waves each own 128 s; contiguous-k short8 loads,
// 16 main MFMA + 4 ones-A MFMA (ksum) per 32-s step. LDS cross-wave reduce.
__global__ __launch_bounds__(256) void kv_kernel(const unsigned short* __restrict__ kT,
                                                 const unsigned short* __restrict__ vT,
                                                 float* __restrict__ kvt_part,
                                                 float* __restrict__ ksum_part) {
  const int chunk = blockIdx.x & (NSPLIT - 1);
  const int bh = blockIdx.x >> 4;
  const int tid = threadIdx.x;
  const int wave = tid >> 6, lane = tid & 63;
  const int lrow = lane & 15, quad = lane >> 4;

  __shared__ float ls_acc[4096];
  __shared__ float ls_ksum[64];
  if (tid < 64) ls_ksum[tid] = 0.f;
#pragma unroll
  for (int i = 0; i < 16; i++) ls_acc[tid + 256 * i] = 0.f;

  const unsigned short* vrow = vT + (size_t)bh * 64 * 8192;
  const unsigned short* krow = kT + (size_t)bh * 64 * 8192;
  const int s_w = chunk * CHUNK + wave * 128;

  short8 ones;
#pragma unroll
  for (int j = 0; j < 8; j++) ones[j] = (short)0x3F80; // bf16 1.0

  f32x4 acc[4][4], aks[4];
#pragma unroll
  for (int i = 0; i < 4; i++) {
    aks[i] = zero4();
#pragma unroll
    for (int j = 0; j < 4; j++) acc[i][j] = zero4();
  }

  for (int it = 0; it < 4; it++) {
    const int s0 = s_w + it * 32 + quad * 8;
    short8 af[4], bfr[4];
#pragma unroll
    for (int mi = 0; mi < 4; mi++)
      af[mi] = *(const short8*)(vrow + (size_t)(mi * 16 + lrow) * 8192 + s0);
#pragma unroll
    for (int ni = 0; ni < 4; ni++)
      bfr[ni] = *(const short8*)(krow + (size_t)(ni * 16 + lrow) * 8192 + s0);
#pragma unroll
    for (int ni = 0; ni < 4; ni++) {
      aks[ni] = __builtin_amdgcn_mfma_f32_16x16x32_bf16(ones, bfr[ni], aks[ni], 0, 0, 0);
#pragma unroll
      for (int mi = 0; mi < 4; mi++)
        acc[mi][ni] = __builtin_amdgcn_mfma_f32_16x16x32_bf16(af[mi], bfr[ni], acc[mi][ni], 0, 0, 0);
    }
  }

  __syncthreads();
#pragma unroll
  for (int mi = 0; mi < 4; mi++)
#pragma unroll
    for (int ni = 0; ni < 4; ni++)
#pragma unroll
      for (int r = 0; r < 4; r++)
        atomicAdd(&ls_acc[(mi * 16 + quad * 4 + r) * 64 + ni * 16 + lrow], acc[mi][ni][r]);
  if (quad == 0) {
#pragma unroll
    for (int ni = 0; ni < 4; ni++) atomicAdd(&ls_ksum[ni * 16 + lrow], aks[ni][0]);
  }
  __syncthreads();

  float* op = kvt_part + ((size_t)chunk * 32 + bh) * 4096;
#pragma unroll
  for (int i = 0; i < 16; i++) op[tid + 256 * i] = ls_acc[tid + 256 * i];
  if (tid < 64) ksum_part[((size_t)chunk * 32 + bh) * 64 + tid] = ls_ksum[tid];
}

// ---------------------------------------------------------------------------
__global__ void kv_reduce_kernel(const float* __restrict__ kvt_part,
                                 const float* __restrict__ ksum_part,
                                 unsigned short* __restrict__ kvT,
                                 unsigned short* __restrict__ ksum_bf) {
  const int bh = blockIdx.x >> 2, seg = blockIdx.x & 3;
  const int idx = seg * 1024 + threadIdx.x * 4;
  float4 s = make_float4(0.f, 0.f, 0.f, 0.f);
#pragma unroll
  for (int c = 0; c < NSPLIT; c++) {
    float4 v = *(const float4*)&kvt_part[((size_t)c * 32 + bh) * 4096 + idx];
    s.x += v.x; s.y += v.y; s.z += v.z; s.w += v.w;
  }
  ushort4v o;
  o[0] = f2bf(s.x); o[1] = f2bf(s.y); o[2] = f2bf(s.z); o[3] = f2bf(s.w);
  *(ushort4v*)(kvT + (size_t)bh * 4096 + idx) = o;
  if (seg == 0 && threadIdx.x < 64) {
    float t = 0.f;
#pragma unroll
    for (int c = 0; c < NSPLIT; c++) t += ksum_part[((size_t)c * 32 + bh) * 64 + threadIdx.x];
    ksum_bf[bh * 64 + threadIdx.x] = f2bf(t);
  }
}

// ---------------------------------------------------------------------------
// numerator = phiQ @ KV, qk_sum = phiQ @ ksum (broadcast-column B => extra
// MFMA whose D rows line up lane-for-lane with the numerator rows).
__global__ __launch_bounds__(256) void attn_kernel(const unsigned short* __restrict__ phiQ,
                                                   const unsigned short* __restrict__ kvT,
                                                   const unsigned short* __restrict__ ksum_bf,
                                                   unsigned short* __restrict__ xattn) {
  const int bh = blockIdx.x & 31;
  const int st = blockIdx.x >> 5;
  const int b = bh >> 3, h = bh & 7;
  const int tid = threadIdx.x;
  const int wave = tid >> 6, lane = tid & 63;
  const int lrow = lane & 15, quad = lane >> 4;
  const size_t rowbase = (size_t)b * SEQ + st * 128 + wave * 32;

  f32x4 acc[2][4], aqs[2];
#pragma unroll
  for (int i = 0; i < 2; i++) {
    aqs[i] = zero4();
#pragma unroll
    for (int j = 0; j < 4; j++) acc[i][j] = zero4();
  }

#pragma unroll
  for (int kk = 0; kk < 64; kk += 32) {
    short8 ks = *(const short8*)(ksum_bf + bh * 64 + kk + quad * 8);
    short8 af[2];
#pragma unroll
    for (int mi = 0; mi < 2; mi++)
      af[mi] = *(const short8*)(phiQ + (rowbase + mi * 16 + lrow) * 512 + h * 64 + kk + quad * 8);
#pragma unroll
    for (int mi = 0; mi < 2; mi++)
      aqs[mi] = __builtin_amdgcn_mfma_f32_16x16x32_bf16(af[mi], ks, aqs[mi], 0, 0, 0);
#pragma unroll
    for (int ni = 0; ni < 4; ni++) {
      short8 bfr = *(const short8*)(kvT + (size_t)bh * 4096 + (ni * 16 + lrow) * 64 + kk + quad * 8);
#pragma unroll
      for (int mi = 0; mi < 2; mi++)
        acc[mi][ni] = __builtin_amdgcn_mfma_f32_16x16x32_bf16(af[mi], bfr, acc[mi][ni], 0, 0, 0);
    }
  }
#pragma unroll
  for (int mi = 0; mi < 2; mi++) {
#pragma unroll
    for (int r = 0; r < 4; r++) {
      float inv = 1.f / (aqs[mi][r] + 1e-6f);
      size_t m = rowbase + mi * 16 + quad * 4 + r;
#pragma unroll
      for (int ni = 0; ni < 4; ni++)
        xattn[m * 512 + h * 64 + ni * 16 + lrow] = f2bf(acc[mi][ni][r] * inv);
    }
  }
}

// ---------------------------------------------------------------------------
__global__ __launch_bounds__(256, 2) void out_gemm_kernel(const unsigned short* __restrict__ xattn,
                                                          const unsigned short* __restrict__ wo,
                                                          const float* __restrict__ ob,
                                                          float* __restrict__ out) {
  const int mt = blockIdx.x >> 2, nt = blockIdx.x & 3;
  const int m0 = mt * 128, n0 = nt * 128;
  const int tid = threadIdx.x;
  const int wave = tid >> 6, lane = tid & 63;
  const int lrow = lane & 15, quad = lane >> 4;
  const int m_off = (wave & 1) * 64, n_off = (wave >> 1) * 64;

  __shared__ unsigned short sA[128 * 64];
  __shared__ unsigned short sB[128 * 64];

  const int srow_l = lane >> 3;
  const int kq_l = (lane & 7) ^ srow_l;
  const int swz = lrow & 7;

  f32x4 acc[4][4];
#pragma unroll
  for (int i = 0; i < 4; i++)
#pragma unroll
    for (int j = 0; j < 4; j++) acc[i][j] = zero4();

  for (int k0 = 0; k0 < 512; k0 += 64) {
    __syncthreads();
#pragma unroll
    for (int i = 0; i < 4; i++) {
      int ig = wave * 4 + i;
      size_t roff = (size_t)(ig * 8 + srow_l) * 512 + k0 + kq_l * 8;
      gload_lds16(xattn + (size_t)m0 * 512 + roff, sA + ig * 512);
      gload_lds16(wo + (size_t)n0 * 512 + roff, sB + ig * 512);
    }
    __syncthreads();
#pragma unroll
    for (int kk = 0; kk < 64; kk += 32) {
      const int e8 = (kk >> 3) + quad;
      short8 af[4], bfr[4];
#pragma unroll
      for (int mi = 0; mi < 4; mi++)
        af[mi] = *(const short8*)(sA + (m_off + mi * 16 + lrow) * 64 + (((e8 ^ swz) << 3)));
#pragma unroll
      for (int ni = 0; ni < 4; ni++)
        bfr[ni] = *(const short8*)(sB + (n_off + ni * 16 + lrow) * 64 + (((e8 ^ swz) << 3)));
#pragma unroll
      for (int ni = 0; ni < 4; ni++)
#pragma unroll
        for (int mi = 0; mi < 4; mi++)
          acc[mi][ni] = __builtin_amdgcn_mfma_f32_16x16x32_bf16(af[mi], bfr[ni], acc[mi][ni], 0, 0, 0);
    }
  }
#pragma unroll
  for (int ni = 0; ni < 4; ni++) {
    int n = n0 + n_off + ni * 16 + lrow;
    float bb = ob[n];
#pragma unroll
    for (int mi = 0; mi < 4; mi++)
#pragma unroll
      for (int r = 0; r < 4; r++) {
        int m = m0 + m_off + mi * 16 + quad * 4 + r;
        out[(size_t)m * 512 + n] = acc[mi][ni][r] + bb;
      }
  }
}

// ---------------------------------------------------------------------------
extern "C" void kernel_launch(void* const* d_in, const int* in_sizes, int n_in,
                              void* d_out, int out_size, void* d_ws, size_t ws_size,
                              hipStream_t stream) {
  char* ws = (char*)d_ws;
  size_t off = 0;
  auto alloc = [&](size_t bytes) -> void* {
    void* p = ws + off;
    off += (bytes + 255) & ~(size_t)255;
    return p;
  };
  unsigned short* wbf = (unsigned short*)alloc((size_t)7 * 262144 * 2);     // 3.67 MB
  unsigned short* phiQ = (unsigned short*)alloc((size_t)BSROWS * 512 * 2);  // 33.5 MB
  unsigned short* kT = (unsigned short*)alloc((size_t)BSROWS * 512 * 2);    // 33.5 MB  [bh][d][s]
  unsigned short* vT = (unsigned short*)alloc((size_t)BSROWS * 512 * 2);    // 33.5 MB  [bh][e][s]
  unsigned short* xbf = (unsigned short*)alloc((size_t)3 * BSROWS * 512 * 2); // 100.7 MB
  if (off > ws_size) return; // insufficient workspace; fail visibly

  // xbf region reused after proj_kernel: x_attn + kv partials
  char* xr = (char*)xbf;
  unsigned short* xattn = (unsigned short*)xr;              // 67,108,864 B
  float* kvt_part = (float*)(xr + 67108864);                //  8,388,608 B
  float* ksum_part = (float*)(xr + 75497472);               //    131,072 B
  unsigned short* kvT = (unsigned short*)(xr + 75628544);   //    262,144 B
  unsigned short* ksum_bf = (unsigned short*)(xr + 75890688);

  WPtrs wp;
  for (int i = 0; i < 7; i++) wp.w[i] = (const float*)d_in[3 + i];
  convert_weights_kernel<<<1792, 256, 0, stream>>>(wp, wbf);
  convert_x_kernel<<<24576, 256, 0, stream>>>((const float*)d_in[0], (const float*)d_in[1],
                                              (const float*)d_in[2], xbf);

  ProjArgs pa;
  pa.b1[0] = (const float*)d_in[10]; pa.b2[0] = (const float*)d_in[11];
  pa.b1[1] = (const float*)d_in[12]; pa.b2[1] = (const float*)d_in[13];
  pa.b1[2] = (const float*)d_in[14]; pa.b2[2] = (const float*)d_in[15];
  pa.out[0] = phiQ; pa.out[1] = kT; pa.out[2] = vT;
  proj_kernel<<<dim3(1024, 3), 256, 0, stream>>>(pa, wbf, xbf);

  kv_kernel<<<512, 256, 0, stream>>>(kT, vT, kvt_part, ksum_part);
  kv_reduce_kernel<<<128, 256, 0, stream>>>(kvt_part, ksum_part, kvT, ksum_bf);
  attn_kernel<<<2048, 256, 0, stream>>>(phiQ, kvT, ksum_bf, xattn);
  out_gemm_kernel<<<1024, 256, 0, stream>>>(xattn, wbf + (size_t)6 * 262144,
                                            (const float*)d_in[16], (float*)d_out);
}